// Round 15
// baseline (430.930 us; speedup 1.0000x reference)
//
#include <hip/hip_runtime.h>
#include <hip/hip_bf16.h>
#include <hip/hip_cooperative_groups.h>
#include <stdint.h>

namespace cg = cooperative_groups;

// Problem constants (fixed by the reference)
#define NS   8192
#define XD   512
#define HD   2048
#define YD   512

typedef unsigned short u16;
using bf16x8 = __attribute__((ext_vector_type(8))) short;
using f32x4  = __attribute__((ext_vector_type(4))) float;

__device__ __forceinline__ float bf2f(u16 u) {
  union { uint32_t i; float f; } v; v.i = ((uint32_t)u) << 16; return v.f;
}
__device__ __forceinline__ u16 f2b(float f) {
  __hip_bfloat16 hb = __float2bfloat16(f);
  return *(const u16*)&hb;
}
__device__ __forceinline__ float ld_in(const void* p, int f32, size_t i) {
  return f32 ? ((const float*)p)[i] : bf2f(((const u16*)p)[i]);
}
#define GLDS(gp, lp) __builtin_amdgcn_global_load_lds( \
    (__attribute__((address_space(1))) void*)(gp),     \
    (__attribute__((address_space(3))) void*)(lp), 16, 0, 0)

// per-block dtype self-detection (R2/3 lesson: MIXED input dtypes; fp32 bits
// read as bf16 are wild/NaN with p~0.46 per low-u16 -> conclusive probe).
__device__ __forceinline__ int probe_f32(const void* p, int n_u16, int* sflag) {
  if (threadIdx.x == 0) *sflag = 0;
  __syncthreads();
  const u16* q = (const u16*)p;
  int wild = 0;
  for (int i = threadIdx.x; i < n_u16; i += blockDim.x) {
    float v = bf2f(q[i]);
    if (!(fabsf(v) <= 1000.0f)) wild = 1;
  }
  if (wild) *sflag = 1;
  __syncthreads();
  int r = *sflag;
  __syncthreads();
  return r;
}

// 64x64 transpose tile (bf16/f32 in -> bf16^T out), tile >= 64*72 u16
__device__ __forceinline__ void transpose64(const void* in, u16* out,
                                            int R, int C, int f, int t,
                                            u16* tile) {
  const int tid = threadIdx.x;
  const int nbx = C >> 6;
  const int c0 = (t % nbx) * 64, r0 = (t / nbx) * 64;
  const int r = tid >> 2, cc = (tid & 3) * 16;
  if (f) {
    const float4* s = (const float4*)((const float*)in + (size_t)(r0 + r) * C + c0 + cc);
#pragma unroll
    for (int k = 0; k < 4; ++k) {
      float4 v = s[k];
      tile[r * 72 + cc + k * 4 + 0] = f2b(v.x);
      tile[r * 72 + cc + k * 4 + 1] = f2b(v.y);
      tile[r * 72 + cc + k * 4 + 2] = f2b(v.z);
      tile[r * 72 + cc + k * 4 + 3] = f2b(v.w);
    }
  } else {
    const uint4* s = (const uint4*)((const u16*)in + (size_t)(r0 + r) * C + c0 + cc);
    *(uint4*)&tile[r * 72 + cc]     = s[0];
    *(uint4*)&tile[r * 72 + cc + 8] = s[1];
  }
  __syncthreads();
  const int i = tid >> 2, jc = (tid & 3) * 16;
  alignas(16) u16 o[16];
#pragma unroll
  for (int j = 0; j < 16; ++j) o[j] = tile[(jc + j) * 72 + i];
  uint4* dq = (uint4*)&out[(size_t)(c0 + i) * R + r0 + jc];
  dq[0] = ((const uint4*)o)[0];
  dq[1] = ((const uint4*)o)[1];
}

// ============================================================================
// R15: ONE persistent cooperative kernel. R13's ledger: kernel-sum ~176 us vs
// 232 total -> ~56 us of inter-dispatch overhead on 3 launches. Phases (R13's
// proven bodies verbatim) separated by grid.sync(); dtype probes hoisted to
// once per block; 48 KB LDS union; grid = blocks/CU x 256 (multiple of 8 so
// the t&7 XCD decode is preserved when tiles stride by gridDim).
// ============================================================================
__global__ __launch_bounds__(256, 3) void fused_all(
    const void* __restrict__ x, const void* __restrict__ y,
    const void* __restrict__ w1m, const void* __restrict__ b1m,
    const void* __restrict__ w2m, const void* __restrict__ b2m,
    const void* __restrict__ w1l, const void* __restrict__ b1l,
    const void* __restrict__ w2l, const void* __restrict__ b2l,
    u16* __restrict__ xb, float* __restrict__ biasv,
    float* __restrict__ Sy, float* __restrict__ Sy2,
    u16* __restrict__ W1t, u16* __restrict__ W2tm, u16* __restrict__ W2tl,
    u16* __restrict__ h_mu, u16* __restrict__ h_lv,
    double* __restrict__ gacc, float* __restrict__ out) {
  __shared__ alignas(16) u16 smem[24576];    // 48 KB phase union
  __shared__ double bs[4];
  __shared__ int sflag;
  const int tid = threadIdx.x;
  const int bid = blockIdx.x;
  const int nblk = gridDim.x;

  // ---- hoisted dtype probes (once per block, was once per prep item) ----
  const int xf   = probe_f32(x,   1024, &sflag);
  const int yf   = probe_f32(y,   1024, &sflag);
  const int fw1m = probe_f32(w1m, 1024, &sflag);
  const int fw2m = probe_f32(w2m, 1024, &sflag);
  const int fw1l = probe_f32(w1l, 1024, &sflag);
  const int fw2l = probe_f32(w2l, 1024, &sflag);
  const int fb1m = probe_f32(b1m, 1024, &sflag);
  const int fb2m = probe_f32(b2m, 512,  &sflag);
  const int fb1l = probe_f32(b1l, 1024, &sflag);
  const int fb2l = probe_f32(b2l, 512,  &sflag);

  // ================= phase 0: prep (R13 bodies) =================
  // items: [0,64) ystats | [64,2112) x-convert | 2112 biases+zero |
  //        [2113,3137) 64x64 transposes
  for (int w = bid; w < 3137; w += nblk) {
    if (w < 64) {                            // ystats: cols [8w, 8w+8), atomic-free
      const int c0 = w * 8;
      float s[8] = {}, q[8] = {};
      if (yf) {
        const float* fy = (const float*)y + c0;
        for (int r = tid; r < NS; r += 256) {
          const float4 a = *(const float4*)(fy + (size_t)r * YD);
          const float4 c = *(const float4*)(fy + (size_t)r * YD + 4);
          s[0]+=a.x; q[0]+=a.x*a.x; s[1]+=a.y; q[1]+=a.y*a.y;
          s[2]+=a.z; q[2]+=a.z*a.z; s[3]+=a.w; q[3]+=a.w*a.w;
          s[4]+=c.x; q[4]+=c.x*c.x; s[5]+=c.y; q[5]+=c.y*c.y;
          s[6]+=c.z; q[6]+=c.z*c.z; s[7]+=c.w; q[7]+=c.w*c.w;
        }
      } else {
        const u16* hy = (const u16*)y + c0;
        for (int r = tid; r < NS; r += 256) {
          const uint4 t4 = *(const uint4*)(hy + (size_t)r * YD);
          const uint32_t w4[4] = {t4.x, t4.y, t4.z, t4.w};
#pragma unroll
          for (int j = 0; j < 4; ++j) {
            const float v0 = bf2f((u16)(w4[j] & 0xffff));
            const float v1 = bf2f((u16)(w4[j] >> 16));
            s[2*j]   += v0; q[2*j]   += v0 * v0;
            s[2*j+1] += v1; q[2*j+1] += v1 * v1;
          }
        }
      }
      float* red = (float*)smem;             // 8 KB, two passes
#pragma unroll
      for (int j = 0; j < 8; ++j) red[j * 256 + tid] = s[j];
      __syncthreads();
      for (int st = 128; st > 0; st >>= 1) {
        if (tid < st)
#pragma unroll
          for (int j = 0; j < 8; ++j) red[j * 256 + tid] += red[j * 256 + tid + st];
        __syncthreads();
      }
      if (tid < 8) Sy[c0 + tid] = red[tid * 256];
      __syncthreads();
#pragma unroll
      for (int j = 0; j < 8; ++j) red[j * 256 + tid] = q[j];
      __syncthreads();
      for (int st = 128; st > 0; st >>= 1) {
        if (tid < st)
#pragma unroll
          for (int j = 0; j < 8; ++j) red[j * 256 + tid] += red[j * 256 + tid + st];
        __syncthreads();
      }
      if (tid < 8) Sy2[c0 + tid] = red[tid * 256];
    } else if (w < 2112) {                   // x conversion (only if f32)
      if (xf) {
        const size_t base = (size_t)(w - 64) * 2048 + (size_t)tid * 8;
        alignas(16) u16 o[8];
        const float4* s = (const float4*)((const float*)x + base);
        float4 v0 = s[0], v1 = s[1];
        o[0]=f2b(v0.x); o[1]=f2b(v0.y); o[2]=f2b(v0.z); o[3]=f2b(v0.w);
        o[4]=f2b(v1.x); o[5]=f2b(v1.y); o[6]=f2b(v1.z); o[7]=f2b(v1.w);
        *(uint4*)(xb + base) = *(const uint4*)o;
      }
    } else if (w == 2112) {                  // biases -> f32, zero gacc
      if (tid == 0) *gacc = 0.0;
      for (int i = tid; i < 5120; i += 256) {
        float v;
        if (i < 2048)      v = ld_in(b1m, fb1m, i);
        else if (i < 4096) v = ld_in(b1l, fb1l, i - 2048);
        else if (i < 4608) v = ld_in(b2m, fb2m, i - 4096);
        else               v = ld_in(b2l, fb2l, i - 4608);
        biasv[i] = v;
      }
    } else {                                 // 64x64-tile transposes
      const int id = w - 2113, which = id >> 8, t = id & 255;
      const void* in; u16* out2; int R, C, f;
      if (which == 0)      { in = w1m; out2 = W1t;                   R = XD; C = HD; f = fw1m; }
      else if (which == 1) { in = w2m; out2 = W2tm;                  R = HD; C = YD; f = fw2m; }
      else if (which == 2) { in = w1l; out2 = W1t + (size_t)HD * XD; R = XD; C = HD; f = fw1l; }
      else                 { in = w2l; out2 = W2tl;                  R = HD; C = YD; f = fw2l; }
      transpose64(in, out2, R, C, f, t, smem);
    }
    __syncthreads();                         // smem reuse across items
  }
  cg::this_grid().sync();

  // ================= phase 1: gemm1 (R13/R6 body verbatim) =================
  // h_{mu,lv} = relu(x @ [W1m|W1l] + b1); 128x128, BK=64, XOR-swizzled LDS.
  {
    const u16* A = xf ? xb : (const u16*)x;
    u16* As = smem;                          // 16 KB
    u16* Bs = smem + 8192;                   // 16 KB
    const int wid = tid >> 6, lane = tid & 63;
    const int quad = lane >> 4, c16 = lane & 15, cswz = c16 & 7;
    const int srow = lane >> 3, sc = lane & 7;
    const int scg  = (sc ^ srow) * 8;
    const int mrow = (wid >> 1) * 64, ncol = (wid & 1) * 64;

    for (int t = bid; t < 2048; t += nblk) { // nblk % 8 == 0 -> t&7 = bid&7
      const int xcd = t & 7, slot = t >> 3;
      const int bm0 = (xcd * 8 + slot / 32) * 128;
      const int bn0 = (slot % 32) * 128;
      f32x4 acc[4][4] = {};

      for (int k0 = 0; k0 < XD; k0 += 64) {
#pragma unroll
        for (int j = 0; j < 4; ++j) {
          const int grp = wid * 4 + j, row = grp * 8 + srow;
          GLDS(A   + (size_t)(bm0 + row) * XD + (k0 + scg), As + grp * 512);
          GLDS(W1t + (size_t)(bn0 + row) * XD + (k0 + scg), Bs + grp * 512);
        }
        __syncthreads();
#pragma unroll
        for (int h = 0; h < 2; ++h) {
          const int off = ((h * 4 + quad) ^ cswz) * 8;
          bf16x8 af[4], bfr[4];
#pragma unroll
          for (int mi = 0; mi < 4; ++mi)
            af[mi] = *(const bf16x8*)&As[(mrow + mi * 16 + c16) * 64 + off];
#pragma unroll
          for (int ni = 0; ni < 4; ++ni)
            bfr[ni] = *(const bf16x8*)&Bs[(ncol + ni * 16 + c16) * 64 + off];
#pragma unroll
          for (int mi = 0; mi < 4; ++mi)
#pragma unroll
            for (int ni = 0; ni < 4; ++ni)
              acc[mi][ni] = __builtin_amdgcn_mfma_f32_16x16x32_bf16(
                  af[mi], bfr[ni], acc[mi][ni], 0, 0, 0);
        }
        __syncthreads();
      }

      // Epilogue (C/D layout m89: col = lane&15, row = quad*4 + reg)
      const bool is_lv = bn0 >= HD;
      u16* dst = is_lv ? h_lv : h_mu;
      const int cb = bn0 - (is_lv ? HD : 0);
#pragma unroll
      for (int ni = 0; ni < 4; ++ni) {
        const int gc = ncol + ni * 16 + c16;
        const float bv = biasv[bn0 + gc];
#pragma unroll
        for (int mi = 0; mi < 4; ++mi)
#pragma unroll
          for (int r = 0; r < 4; ++r) {
            const int grow = bm0 + mrow + mi * 16 + quad * 4 + r;
            dst[(size_t)grow * HD + (cb + gc)] = f2b(fmaxf(acc[mi][ni][r] + bv, 0.f));
          }
      }
    }
  }
  cg::this_grid().sync();

  // ================= phase 2: gemm2 dual + loss (R13 body verbatim) ========
  {
    const float* b2mv = biasv + 4096;
    const float* b2lv = biasv + 4608;
    u16* Am = smem;                          // 8 KB
    u16* Al = smem + 4096;                   // 8 KB
    u16* Bm = smem + 8192;                   // 16 KB
    u16* Bl = smem + 16384;                  // 16 KB
    const int wid = tid >> 6, lane = tid & 63;
    const int quad = lane >> 4, c16 = lane & 15, cswz = c16 & 7;
    const int srow = lane >> 3, sc = lane & 7;
    const int scg  = (sc ^ srow) * 8;
    const int mrow = (wid >> 1) * 32, ncol = (wid & 1) * 64;
    const float invN = 1.0f / (float)NS;

    for (int t = bid; t < 512; t += nblk) {
      const int xcd = t & 7, slot = t >> 3;
      const int bm0 = (xcd * 16 + slot / 4) * 64;
      const int bn0 = (slot % 4) * 128;
      f32x4 am[2][4] = {}, al[2][4] = {};

      for (int k0 = 0; k0 < HD; k0 += 64) {
#pragma unroll
        for (int j = 0; j < 2; ++j) {        // h tiles: 64 rows
          const int grp = wid * 2 + j, row = grp * 8 + srow;
          const size_t go = (size_t)(bm0 + row) * HD + (k0 + scg);
          GLDS(h_mu + go, Am + grp * 512);
          GLDS(h_lv + go, Al + grp * 512);
        }
#pragma unroll
        for (int j = 0; j < 4; ++j) {        // W2 tiles: 128 rows
          const int grp = wid * 4 + j, row = grp * 8 + srow;
          const size_t go = (size_t)(bn0 + row) * HD + (k0 + scg);
          GLDS(W2tm + go, Bm + grp * 512);
          GLDS(W2tl + go, Bl + grp * 512);
        }
        __syncthreads();
#pragma unroll
        for (int h = 0; h < 2; ++h) {
          const int off = ((h * 4 + quad) ^ cswz) * 8;
          bf16x8 afm[2], afl[2], bfm[4], bfl[4];
#pragma unroll
          for (int mi = 0; mi < 2; ++mi) {
            const int rl = (mrow + mi * 16 + c16) * 64 + off;
            afm[mi] = *(const bf16x8*)&Am[rl];
            afl[mi] = *(const bf16x8*)&Al[rl];
          }
#pragma unroll
          for (int ni = 0; ni < 4; ++ni) {
            const int rl = (ncol + ni * 16 + c16) * 64 + off;
            bfm[ni] = *(const bf16x8*)&Bm[rl];
            bfl[ni] = *(const bf16x8*)&Bl[rl];
          }
#pragma unroll
          for (int mi = 0; mi < 2; ++mi)
#pragma unroll
            for (int ni = 0; ni < 4; ++ni) {
              am[mi][ni] = __builtin_amdgcn_mfma_f32_16x16x32_bf16(
                  afm[mi], bfm[ni], am[mi][ni], 0, 0, 0);
              al[mi][ni] = __builtin_amdgcn_mfma_f32_16x16x32_bf16(
                  afl[mi], bfl[ni], al[mi][ni], 0, 0, 0);
            }
        }
        __syncthreads();
      }

      // Fused loss epilogue: mu & lvp in registers.
      float s = 0.f;
#pragma unroll
      for (int ni = 0; ni < 4; ++ni) {
        const int gcol = bn0 + ncol + ni * 16 + c16;
        const float bmv = b2mv[gcol], blv = b2lv[gcol];
        const float syv = Sy[gcol], sy2v = Sy2[gcol];
#pragma unroll
        for (int mi = 0; mi < 2; ++mi)
#pragma unroll
          for (int r = 0; r < 4; ++r) {
            const int grow = bm0 + mrow + mi * 16 + quad * 4 + r;
            const float m   = am[mi][ni][r] + bmv;
            const float lvp = al[mi][ni][r] + blv;
            const float wq  = 0.5f * expf(-tanhf(lvp));
            const float yv  = ld_in(y, yf, (size_t)grow * YD + gcol);
            s += wq * (yv * yv - 2.f * m * yv + (2.f * m * syv - sy2v) * invN);
          }
      }
      for (int off = 32; off > 0; off >>= 1) s += __shfl_down(s, off);
      if (lane == 0) bs[wid] = (double)s;
      __syncthreads();
      if (tid == 0) atomicAdd(gacc, bs[0] + bs[1] + bs[2] + bs[3]);
      __syncthreads();
    }
  }
  cg::this_grid().sync();
  if (bid == 0 && tid == 0)
    out[0] = (float)(-gacc[0] / (double)NS); // fp32 output (R2 evidence)
}

// ---------------- launch: ONE cooperative dispatch --------------------------
extern "C" void kernel_launch(void* const* d_in, const int* in_sizes, int n_in,
                              void* d_out, int out_size, void* d_ws, size_t ws_size,
                              hipStream_t stream) {
  char* ws = (char*)d_ws;
  double* gacc  = (double*)ws;                   // zeroed in phase 0
  float*  Sy    = (float*)(ws + 128);            // 512 f32
  float*  Sy2   = (float*)(ws + 2176);           // 512 f32
  float*  biasv = (float*)(ws + 4224);           // 5120 f32 -> ends 24704
  u16* xb   = (u16*)(ws + 24704);                // [NS,XD] bf16, 8 MB
  u16* W1t  = xb + (size_t)NS * XD;              // [4096,512] 4 MB
  u16* W2tm = W1t + (size_t)2 * HD * XD;         // [YD,HD] 2 MB
  u16* W2tl = W2tm + (size_t)YD * HD;            // 2 MB
  u16* h_mu = W2tl + (size_t)YD * HD;            // 32 MB
  u16* h_lv = h_mu + (size_t)NS * HD;            // 32 MB (~80 MB total)

  int nb = 0;
  hipOccupancyMaxActiveBlocksPerMultiprocessor(&nb, fused_all, 256, 0);
  if (nb < 1) nb = 1;
  if (nb > 4) nb = 4;
  dim3 grid((unsigned)nb * 256u);                // multiple of 8 (XCD decode)

  const void* x_   = d_in[0]; const void* y_   = d_in[1];
  const void* w1m_ = d_in[2]; const void* b1m_ = d_in[3];
  const void* w2m_ = d_in[4]; const void* b2m_ = d_in[5];
  const void* w1l_ = d_in[6]; const void* b1l_ = d_in[7];
  const void* w2l_ = d_in[8]; const void* b2l_ = d_in[9];
  float* out_ = (float*)d_out;

  void* args[] = {
      (void*)&x_, (void*)&y_,
      (void*)&w1m_, (void*)&b1m_, (void*)&w2m_, (void*)&b2m_,
      (void*)&w1l_, (void*)&b1l_, (void*)&w2l_, (void*)&b2l_,
      (void*)&xb, (void*)&biasv, (void*)&Sy, (void*)&Sy2,
      (void*)&W1t, (void*)&W2tm, (void*)&W2tl,
      (void*)&h_mu, (void*)&h_lv,
      (void*)&gacc, (void*)&out_};

  hipLaunchCooperativeKernel(fused_all, grid, dim3(256), args, 0, stream);
}